// Round 17
// baseline (558.700 us; speedup 1.0000x reference)
//
#include <hip/hip_runtime.h>
#include <hip/hip_cooperative_groups.h>

namespace cg = cooperative_groups;

#define S 2048
#define HID 2048
#define NH 16
#define DH 128
#define VOC 128
#define LCAP 128
#define K2EXP 0.12752551286084112f   // (1/sqrt(128)) * log2(e)
#define RTHR 62.0f                   // defer-max threshold in raw-score units
#define NEGS -3.0e38f

typedef __bf16 bf16_t;
typedef __attribute__((ext_vector_type(8))) __bf16 bf16x8;
typedef __attribute__((ext_vector_type(4))) __bf16 bf16x4;
typedef __attribute__((ext_vector_type(4))) float f32x4;
typedef __attribute__((ext_vector_type(16))) float f32x16;

#define MFMA16 __builtin_amdgcn_mfma_f32_16x16x32_bf16
#define MFMA32 __builtin_amdgcn_mfma_f32_32x32x16_bf16

__device__ __forceinline__ unsigned cvtpk(float lo, float hi) {
  unsigned r;
  asm("v_cvt_pk_bf16_f32 %0, %1, %2" : "=v"(r) : "v"(lo), "v"(hi));
  return r;
}
__device__ __forceinline__ void plswap(unsigned& a, unsigned& b) {
  asm volatile("v_permlane32_swap_b32 %0, %1" : "+v"(a), "+v"(b));
}
__device__ __forceinline__ bf16x8 mk8(unsigned d0, unsigned d1, unsigned d2, unsigned d3) {
  union { unsigned u[4]; bf16x8 v; } x;
  x.u[0] = d0; x.u[1] = d1; x.u[2] = d2; x.u[3] = d3;
  return x.v;
}

// Tile layouts (per head h, 32-kv tile t; contiguous 4096 halfwords = 8KB):
//  ktb[(h*64+t)*4096 + row*128 + c*8 + e] = hid[32t+row][h*DH + 8*(c^(row&7)) + e]
//  vtb[(h*64+t)*4096 + d*32   + c*8 + e] = hid[32t + 8*(c^(d&3)) + e][h*DH + d]

// ---------------- mask precompute ----------------
__global__ __launch_bounds__(256) void maskprep2(const int* __restrict__ tokens,
                                                 const unsigned char* __restrict__ seg,
                                                 const unsigned char* __restrict__ spc,
                                                 int4* __restrict__ mi,
                                                 int* __restrict__ lq,
                                                 unsigned long long* __restrict__ lmask,
                                                 int2* __restrict__ smeta) {
  __shared__ int ssp[257], ssg[257], smw[257], sms[257], sfl[257];
  __shared__ int fpre[2048];
  __shared__ int ns64[64];
  __shared__ unsigned long long lmk[32];
  __shared__ int cdet[2];
  int t = threadIdx.x;
  if (t < 2) cdet[t] = 0;
  if (t < 32) lmk[t] = 0ull;
  __syncthreads();
  {
    int nz = ((t & 3) != 0 && seg[t]) ? 1 : 0;
    int fc = ((t & 3) == 3 && seg[t] == 0x3f) ? 1 : 0;
    if (nz) atomicAdd(&cdet[0], 1);
    if (fc) atomicAdd(&cdet[1], 1);
  }
  __syncthreads();
  int lay = (cdet[1] > 8) ? 2 : ((cdet[0] > 4) ? 1 : 0);
  auto getb = [&](const unsigned char* p, int i) -> int {
    if (lay == 1) return p[i] != 0;
    if (lay == 2) return ((const float*)p)[i] != 0.f;
    return ((const int*)p)[i] != 0;
  };
  int base = t * 8;
  int spv[8], sgv[8], npv[8], fv[8];
  int a = 0, b = 0, mw = 0, ms = 0, fs = 0;
  for (int j = 0; j < 8; j++) {
    int i = base + j;
    spv[j] = getb(spc, i);
    sgv[j] = 1 - getb(seg, i);
    npv[j] = (tokens[i] != 127) ? 1 : 0;
    fv[j] = spv[j] & sgv[j] & npv[j];
    a += spv[j]; b += sgv[j]; fs += fv[j];
    if (i >= 1 && spv[j]) mw = (i + 1 > mw) ? i + 1 : mw;
    if (i >= 1 && sgv[j]) ms = (i + 1 > ms) ? i + 1 : ms;
  }
  ssp[t + 1] = a; ssg[t + 1] = b; smw[t + 1] = mw; sms[t + 1] = ms; sfl[t + 1] = fs;
  if (t == 0) { ssp[0] = 0; ssg[0] = 0; smw[0] = 0; sms[0] = 0; sfl[0] = 0; }
  __syncthreads();
  for (int off = 1; off < 256; off <<= 1) {
    int v0 = 0, v1 = 0, v2 = 0, v3 = 0, v4 = 0;
    if (t + 1 > off) { v0 = ssp[t+1-off]; v1 = ssg[t+1-off]; v2 = smw[t+1-off]; v3 = sms[t+1-off]; v4 = sfl[t+1-off]; }
    __syncthreads();
    ssp[t + 1] += v0; ssg[t + 1] += v1;
    if (v2 > smw[t + 1]) smw[t + 1] = v2;
    if (v3 > sms[t + 1]) sms[t + 1] = v3;
    sfl[t + 1] += v4;
    __syncthreads();
  }
  if ((t & 3) == 0) {
    int ws = smw[t], ss = sms[t];
    ns64[t >> 2] = ws < ss ? ws : ss;
  }
  int esp = ssp[t], esg = ssg[t], ef = sfl[t];
  for (int j = 0; j < 8; j++) {
    int i = base + j;
    int wint = (i == 0) ? (1 + spv[j]) : (1 + esp);
    int sint = (i == 0) ? (1 + sgv[j]) : (1 + esg);
    mi[i] = make_int4(npv[j] | (spv[j] << 1) | (sgv[j] << 2), wint, sint, 0);
    fpre[i] = ef;
    int lqv = (fv[j] && ef < LCAP) ? ef : -1;
    lq[i] = lqv;
    if (lqv >= 0) atomicOr(&lmk[i >> 6], 1ull << (i & 63));
    esp += spv[j]; esg += sgv[j]; ef += fv[j];
  }
  __syncthreads();
  if (t < 32) lmask[t] = lmk[t];
  if (t < 64) {
    int nsTile = ns64[t] >> 5;
    int lc = fpre[nsTile * 32];
    if (lc > LCAP) lc = LCAP;
    smeta[t] = make_int2(nsTile, lc);
  }
}

// ---------------- megaprep: embed(ktb/vtb/landmarks) + bitgen + wcvt ----------------
__global__ __launch_bounds__(256) void megaprep(const int* __restrict__ tokens,
                                                const float* __restrict__ emb,
                                                const int4* __restrict__ mi,
                                                const int* __restrict__ lq,
                                                const unsigned long long* __restrict__ lmask,
                                                const float* __restrict__ lm_w,
                                                bf16_t* __restrict__ wbf,
                                                unsigned* __restrict__ cmask,
                                                bf16_t* __restrict__ ktb,
                                                bf16_t* __restrict__ vtb,
                                                bf16_t* __restrict__ ktbL,
                                                bf16_t* __restrict__ vtbL) {
  __shared__ __align__(16) bf16_t tile[64 * 136];
  int bid = blockIdx.x;
  int tid = threadIdx.x;

  if (bid < 512) {
    int qblk = bid & 31, h = bid >> 5;
    int q0 = qblk * 64;
    int ql = tid >> 2, d0 = (tid & 3) * 32;
    int tok = tokens[q0 + ql];
    const float4* src = (const float4*)(emb + (size_t)tok * HID + h * DH + d0);
    #pragma unroll
    for (int i = 0; i < 8; i++) {
      float4 f = src[i];
      tile[ql * 136 + d0 + i * 4 + 0] = (bf16_t)f.x;
      tile[ql * 136 + d0 + i * 4 + 1] = (bf16_t)f.y;
      tile[ql * 136 + d0 + i * 4 + 2] = (bf16_t)f.z;
      tile[ql * 136 + d0 + i * 4 + 3] = (bf16_t)f.w;
    }
    __syncthreads();
    {
      int tl2 = tid >> 7, half = (tid >> 6) & 1, lane = tid & 63;
      bf16_t* kt = ktb + ((size_t)(h * 64) + 2 * qblk + tl2) * 4096;
      #pragma unroll
      for (int k = 0; k < 4; k++) {
        int s = half * 4 + k;
        int row = s * 4 + (lane >> 4);
        int c = lane & 15;
        bf16x8 v;
        #pragma unroll
        for (int e = 0; e < 8; e++)
          v[e] = tile[(32 * tl2 + row) * 136 + 8 * (c ^ (row & 7)) + e];
        *(bf16x8*)(kt + s * 512 + lane * 8) = v;
      }
    }
    {
      int tl2 = tid >> 7, d = tid & 127;
      bf16_t* vt = vtb + ((size_t)(h * 64) + 2 * qblk + tl2) * 4096;
      #pragma unroll
      for (int c = 0; c < 4; c++) {
        bf16x8 v;
        #pragma unroll
        for (int e = 0; e < 8; e++)
          v[e] = tile[(32 * tl2 + 8 * (c ^ (d & 3)) + e) * 136 + d];
        *(bf16x8*)(vt + d * 32 + c * 8) = v;
      }
    }
    unsigned long long lm = lmask[q0 >> 6];
    while (lm) {
      int r = __builtin_ctzll(lm);
      lm &= lm - 1;
      int li = lq[q0 + r];
      if (li >= 0 && tid < 128) {
        int dd = tid;
        bf16_t vv = tile[r * 136 + dd];
        int row = li & 31, jt = li >> 5;
        ktbL[((size_t)(h * 4) + jt) * 4096 + row * 128 + ((dd >> 3) ^ (row & 7)) * 8 + (dd & 7)] = vv;
        vtbL[((size_t)(h * 4) + jt) * 4096 + dd * 32 + ((row >> 3) ^ (dd & 3)) * 8 + (row & 7)] = vv;
      }
    }
  } else if (bid < 1024) {
    __shared__ int4 km[32];
    int b2 = bid - 512;
    int w = b2 & 63, y = b2 >> 6;
    int q = y * 256 + tid;
    if (tid < 32) km[tid] = mi[w * 32 + tid];
    __syncthreads();
    int4 mq = mi[q];
    unsigned word = 0;
    #pragma unroll
    for (int j = 0; j < 32; j++) {
      int kv = w * 32 + j;
      int4 mk = km[j];
      bool v = ((mq.x & mk.x) & 1) &&
               ((mk.x & 2) || (mq.y == mk.y)) &&
               ((mk.x & 4) || (mq.z == mk.z)) &&
               (kv <= q);
      word |= (v ? 1u : 0u) << j;
    }
    cmask[(size_t)w * S + q] = word;
  } else {
    int i = (bid - 1024) * 256 + tid;
    float4 f = ((const float4*)lm_w)[i];
    bf16x4 v;
    v[0] = (bf16_t)f.x; v[1] = (bf16_t)f.y; v[2] = (bf16_t)f.z; v[3] = (bf16_t)f.w;
    *(bf16x4*)(wbf + (size_t)i * 4) = v;
  }
}

// ---------------- shared per-layer attention body ----------------
__device__ __forceinline__ void attn_layer(int h, int st, int nsT, int lcount,
                                           int l, int l31, int hi, int q0, int q,
                                           int npq, int swz,
                                           const unsigned* __restrict__ cmask,
                                           const int* __restrict__ lq,
                                           const unsigned long long* __restrict__ lmask,
                                           const bf16_t* __restrict__ ktb,
                                           const bf16_t* __restrict__ vtb,
                                           const bf16_t* __restrict__ ktbL,
                                           const bf16_t* __restrict__ vtbL,
                                           bf16_t* __restrict__ oktb,
                                           bf16_t* __restrict__ ovtb,
                                           bf16_t* __restrict__ oktbL,
                                           bf16_t* __restrict__ ovtbL,
                                           bf16_t* __restrict__ hbF,
                                           int writeT,
                                           bf16_t* tl) {
  int nNear = st + 1 - nsT;
  int nLT = (lcount + 31) >> 5;
  int nIter = nNear + nLT;

  bf16x8 qf[8];
  {
    const bf16_t* kt0 = ktb + ((size_t)(h * 64) + st) * 4096;
    #pragma unroll
    for (int ks = 0; ks < 8; ks++)
      qf[ks] = *(const bf16x8*)(kt0 + l31 * 128 + (((2 * ks + hi) ^ swz) * 8));
  }

  f32x16 acc[4];
  #pragma unroll
  for (int i = 0; i < 4; i++)
    #pragma unroll
    for (int r = 0; r < 16; r++) acc[i][r] = 0.f;
  float m = -1e30f, lsum = 0.f;

  auto LOADT = [&](int i, bf16x8* kf, bf16x8* vf) {
    const bf16_t* Ktile; const bf16_t* Vtile;
    if (i < nNear) {
      int t = nsT + i;
      Ktile = ktb + ((size_t)(h * 64) + t) * 4096;
      Vtile = vtb + ((size_t)(h * 64) + t) * 4096;
    } else {
      int j = i - nNear;
      Ktile = ktbL + ((size_t)(h * 4) + j) * 4096;
      Vtile = vtbL + ((size_t)(h * 4) + j) * 4096;
    }
    const bf16_t* kp = Ktile + l31 * 128;
    #pragma unroll
    for (int ks = 0; ks < 8; ks++)
      kf[ks] = *(const bf16x8*)(kp + (((2 * ks + hi) ^ swz) * 8));
    #pragma unroll
    for (int j2 = 0; j2 < 8; j2++) {
      int db = j2 >> 1, ks = j2 & 1;
      vf[j2] = *(const bf16x8*)(Vtile + (size_t)(32 * db + l31) * 32 + (((2 * ks + hi) ^ (l31 & 3)) * 8));
    }
  };

  auto COMPUTE = [&](int i, const bf16x8* kf, const bf16x8* vf) {
    unsigned w0;
    if (i < nNear) {
      w0 = cmask[(size_t)(nsT + i) * S + q];
    } else {
      int rem = lcount - (i - nNear) * 32;
      w0 = (rem >= 32) ? 0xffffffffu : ((rem <= 0) ? 0u : ((1u << rem) - 1u));
      w0 = npq ? w0 : 0u;
    }
    if (!__any(w0 != 0u)) return;

    f32x16 sA, sB;
    #pragma unroll
    for (int r = 0; r < 16; r++) { sA[r] = 0.f; sB[r] = 0.f; }
    #pragma unroll
    for (int ks = 0; ks < 8; ks += 2) {
      sA = MFMA32(kf[ks], qf[ks], sA, 0, 0, 0);
      sB = MFMA32(kf[ks + 1], qf[ks + 1], sB, 0, 0, 0);
    }

    float sv[16];
    #pragma unroll
    for (int r = 0; r < 16; r++) {
      int bit = (r & 3) + 8 * (r >> 2) + 4 * hi;
      float sr = sA[r] + sB[r];
      sv[r] = ((w0 >> bit) & 1u) ? sr : NEGS;
    }
    float t0 = fmaxf(fmaxf(sv[0], sv[1]), fmaxf(sv[2], sv[3]));
    float t1 = fmaxf(fmaxf(sv[4], sv[5]), fmaxf(sv[6], sv[7]));
    float t2 = fmaxf(fmaxf(sv[8], sv[9]), fmaxf(sv[10], sv[11]));
    float t3 = fmaxf(fmaxf(sv[12], sv[13]), fmaxf(sv[14], sv[15]));
    float mx = fmaxf(fmaxf(t0, t1), fmaxf(t2, t3));
    mx = fmaxf(mx, __shfl_xor(mx, 32, 64));
    if (__any(mx > m + RTHR)) {
      float mn = fmaxf(m, mx);
      float al = exp2f((m - mn) * K2EXP);
      m = mn; lsum *= al;
      #pragma unroll
      for (int r = 0; r < 16; r++) {
        float alr = __shfl(al, (r & 3) + 8 * (r >> 2) + 4 * hi, 64);
        #pragma unroll
        for (int d = 0; d < 4; d++) acc[d][r] *= alr;
      }
    }
    float mk = m * K2EXP;
    float p[16];
    #pragma unroll
    for (int r = 0; r < 16; r++)
      p[r] = exp2f(__builtin_fmaf(sv[r], K2EXP, -mk));
    float u0 = (p[0] + p[1]) + (p[2] + p[3]);
    float u1 = (p[4] + p[5]) + (p[6] + p[7]);
    float u2 = (p[8] + p[9]) + (p[10] + p[11]);
    float u3 = (p[12] + p[13]) + (p[14] + p[15]);
    float ps = (u0 + u1) + (u2 + u3);
    ps += __shfl_xor(ps, 32, 64);
    lsum += ps;

    bf16x8 pa[2];
    {
      unsigned a0 = cvtpk(p[0], p[1]),   a1 = cvtpk(p[2], p[3]);
      unsigned b0 = cvtpk(p[4], p[5]),   b1 = cvtpk(p[6], p[7]);
      unsigned a2 = cvtpk(p[8], p[9]),   a3 = cvtpk(p[10], p[11]);
      unsigned b2 = cvtpk(p[12], p[13]), b3 = cvtpk(p[14], p[15]);
      plswap(a0, b0); plswap(a1, b1); plswap(a2, b2); plswap(a3, b3);
      pa[0] = mk8(a0, a1, b0, b1);
      pa[1] = mk8(a2, a3, b2, b3);
    }

    #pragma unroll
    for (int db = 0; db < 4; db++) {
      #pragma unroll
      for (int ks = 0; ks < 2; ks++)
        acc[db] = MFMA32(pa[ks], vf[db * 2 + ks], acc[db], 0, 0, 0);
    }
  };

  bf16x8 kfA[8], vfA[8], kfB[8], vfB[8];
  LOADT(0, kfA, vfA);
  for (int i = 0; i < nIter; i += 2) {
    if (i + 1 < nIter) LOADT(i + 1, kfB, vfB);
    COMPUTE(i, kfA, vfA);
    if (i + 2 < nIter) LOADT(i + 2, kfA, vfA);
    if (i + 1 < nIter) COMPUTE(i + 1, kfB, vfB);
  }

  float inv = (lsum > 0.f) ? 1.f / lsum : 0.f;
  #pragma unroll
  for (int r = 0; r < 16; r++) {
    int qr = (r & 3) + 8 * (r >> 2) + 4 * hi;
    float ivr = __shfl(inv, qr, 64);
    #pragma unroll
    for (int db = 0; db < 4; db++)
      tl[qr * 132 + db * 32 + l31] = (bf16_t)(acc[db][r] * ivr);
  }
  asm volatile("s_waitcnt lgkmcnt(0)" ::: "memory");
  if (writeT) {
    bf16_t* kt = oktb + ((size_t)(h * 64) + st) * 4096;
    #pragma unroll
    for (int s = 0; s < 8; s++) {
      int row = s * 4 + (l >> 4);
      int c = l & 15;
      bf16x8 v;
      #pragma unroll
      for (int e = 0; e < 8; e++)
        v[e] = tl[row * 132 + 8 * (c ^ (row & 7)) + e];
      *(bf16x8*)(kt + s * 512 + l * 8) = v;
    }
    bf16_t* vt = ovtb + ((size_t)(h * 64) + st) * 4096;
    #pragma unroll
    for (int s = 0; s < 8; s++) {
      int d = s * 16 + (l >> 2);
      bf16x8 v;
      #pragma unroll
      for (int e = 0; e < 8; e++)
        v[e] = tl[(8 * ((l & 3) ^ (d & 3)) + e) * 132 + d];
      *(bf16x8*)(vt + s * 512 + l * 8) = v;
    }
    unsigned lm32 = (unsigned)(lmask[st >> 1] >> ((st & 1) * 32));
    while (lm32) {
      int r = __builtin_ctz(lm32);
      lm32 &= lm32 - 1;
      int li = lq[q0 + r];
      if (li >= 0) {
        int row = li & 31, jt = li >> 5;
        #pragma unroll
        for (int half = 0; half < 2; half++) {
          int dd = l + 64 * half;
          bf16_t vv = tl[r * 132 + dd];
          oktbL[((size_t)(h * 4) + jt) * 4096 + row * 128 + ((dd >> 3) ^ (row & 7)) * 8 + (dd & 7)] = vv;
          ovtbL[((size_t)(h * 4) + jt) * 4096 + dd * 32 + ((row >> 3) ^ (dd & 3)) * 8 + (row & 7)] = vv;
        }
      }
    }
  } else {
    int c4 = l & 3;
    #pragma unroll
    for (int g = 0; g < 2; g++) {
      int row = g * 16 + (l >> 2);
      #pragma unroll
      for (int k = 0; k < 4; k++) {
        bf16x8 v = *(const bf16x8*)(tl + row * 132 + c4 * 32 + k * 8);
        *(bf16x8*)(hbF + (size_t)(q0 + row) * HID + h * DH + c4 * 32 + k * 8) = v;
      }
    }
  }
}

// ---------------- fallback: one layer per dispatch ----------------
__global__ __launch_bounds__(64) void attn10(const bf16_t* __restrict__ ktb,
                                             const bf16_t* __restrict__ vtb,
                                             const bf16_t* __restrict__ ktbL,
                                             const bf16_t* __restrict__ vtbL,
                                             const unsigned* __restrict__ cmask,
                                             const int4* __restrict__ mi,
                                             const int2* __restrict__ smeta,
                                             const int* __restrict__ lq,
                                             const unsigned long long* __restrict__ lmask,
                                             bf16_t* __restrict__ oktb,
                                             bf16_t* __restrict__ ovtb,
                                             bf16_t* __restrict__ oktbL,
                                             bf16_t* __restrict__ ovtbL,
                                             bf16_t* __restrict__ hbF,
                                             int writeT) {
  __shared__ __align__(16) bf16_t tl[32 * 132];
  int h = blockIdx.x, st = blockIdx.y;
  int2 sm = smeta[st];
  int l = threadIdx.x, l31 = l & 31, hi = l >> 5;
  int q0 = 32 * st, q = q0 + l31;
  int npq = mi[q].x & 1;
  int swz = l31 & 7;
  attn_layer(h, st, sm.x, sm.y, l, l31, hi, q0, q, npq, swz,
             cmask, lq, lmask, ktb, vtb, ktbL, vtbL,
             oktb, ovtb, oktbL, ovtbL, hbF, writeT, tl);
}

// ---------------- cooperative: all 4 layers, grid.sync between ----------------
__global__ __launch_bounds__(64) void coop4(const unsigned* __restrict__ cmask,
                                            const int4* __restrict__ mi,
                                            const int2* __restrict__ smeta,
                                            const int* __restrict__ lq,
                                            const unsigned long long* __restrict__ lmask,
                                            bf16_t* __restrict__ kA, bf16_t* __restrict__ vA,
                                            bf16_t* __restrict__ kLA, bf16_t* __restrict__ vLA,
                                            bf16_t* __restrict__ kB, bf16_t* __restrict__ vB,
                                            bf16_t* __restrict__ kLB, bf16_t* __restrict__ vLB,
                                            bf16_t* __restrict__ hbF) {
  __shared__ __align__(16) bf16_t tl[32 * 132];
  cg::grid_group grid = cg::this_grid();
  int h = blockIdx.x, st = blockIdx.y;
  int2 sm = smeta[st];
  int l = threadIdx.x, l31 = l & 31, hi = l >> 5;
  int q0 = 32 * st, q = q0 + l31;
  int npq = mi[q].x & 1;
  int swz = l31 & 7;

  #pragma unroll 1
  for (int L = 0; L < 4; L++) {
    const bf16_t* ik  = (L & 1) ? kB : kA;
    const bf16_t* iv  = (L & 1) ? vB : vA;
    const bf16_t* ikL = (L & 1) ? kLB : kLA;
    const bf16_t* ivL = (L & 1) ? vLB : vLA;
    bf16_t* ok  = (L & 1) ? kA : kB;
    bf16_t* ov  = (L & 1) ? vA : vB;
    bf16_t* okL = (L & 1) ? kLA : kLB;
    bf16_t* ovL = (L & 1) ? vLA : vLB;
    attn_layer(h, st, sm.x, sm.y, l, l31, hi, q0, q, npq, swz,
               cmask, lq, lmask, ik, iv, ikL, ivL,
               ok, ov, okL, ovL, hbF, (L < 3) ? 1 : 0, tl);
    if (L < 3) {
      __threadfence();
      grid.sync();
    }
  }
}

// ---------------- lm head + segment head fused ----------------
__global__ __launch_bounds__(256) void lmseg_head(const bf16_t* __restrict__ hb,
                                                  const bf16_t* __restrict__ wbf,
                                                  const float* __restrict__ bias,
                                                  const float* __restrict__ sw,
                                                  const float* __restrict__ sb,
                                                  float* __restrict__ out,
                                                  float* __restrict__ outseg) {
  __shared__ float red[4][16][130];
  int tid = threadIdx.x;
  int w = tid >> 6, l = tid & 63, l16 = l & 15, g = l >> 4;
  int t0 = blockIdx.x * 16;
  f32x4 acc[8];
  #pragma unroll
  for (int i = 0; i < 8; i++) acc[i] = (f32x4){0.f, 0.f, 0.f, 0.f};
  const bf16_t* arow = hb + (size_t)(t0 + l16) * HID + w * 512;
  for (int k0 = 0; k0 < 512; k0 += 32) {
    bf16x8 af = *(const bf16x8*)(arow + k0 + g * 8);
    #pragma unroll
    for (int vt = 0; vt < 8; vt++) {
      bf16x8 bf_ = *(const bf16x8*)(wbf + (size_t)(vt * 16 + l16) * HID + w * 512 + k0 + g * 8);
      acc[vt] = MFMA16(af, bf_, acc[vt], 0, 0, 0);
    }
  }
  #pragma unroll
  for (int vt = 0; vt < 8; vt++)
    #pragma unroll
    for (int r = 0; r < 4; r++)
      red[w][4 * g + r][vt * 16 + l16] = acc[vt][r];
  __syncthreads();
  int q = tid >> 4, vc = (tid & 15) * 8;
  #pragma unroll
  for (int j = 0; j < 8; j++) {
    float s = red[0][q][vc + j] + red[1][q][vc + j] + red[2][q][vc + j] + red[3][q][vc + j];
    out[(size_t)(t0 + q) * VOC + vc + j] = s + bias[vc + j];
  }
  {
    int c = tid & 15;
    const bf16_t* hrow = hb + (size_t)(t0 + q) * HID + c * 128;
    float s0 = 0.f, s1 = 0.f;
    #pragma unroll
    for (int i = 0; i < 16; i++) {
      bf16x8 v = *(const bf16x8*)(hrow + i * 8);
      const float4* w0p = (const float4*)(sw + c * 128 + i * 8);
      const float4* w1p = (const float4*)(sw + HID + c * 128 + i * 8);
      float4 x0 = w0p[0], x1 = w0p[1], y0 = w1p[0], y1 = w1p[1];
      s0 += (float)v[0]*x0.x + (float)v[1]*x0.y + (float)v[2]*x0.z + (float)v[3]*x0.w
          + (float)v[4]*x1.x + (float)v[5]*x1.y + (float)v[6]*x1.z + (float)v[7]*x1.w;
      s1 += (float)v[0]*y0.x + (float)v[1]*y0.y + (float)v[2]*y0.z + (float)v[3]*y0.w
          + (float)v[4]*y1.x + (float)v[5]*y1.y + (float)v[6]*y1.z + (float)v[7]*y1.w;
    }
    #pragma unroll
    for (int off = 1; off < 16; off <<= 1) {
      s0 += __shfl_xor(s0, off, 64);
      s1 += __shfl_xor(s1, off, 64);
    }
    if (c == 0) {
      outseg[(size_t)(t0 + q) * 2] = s0 + sb[0];
      outseg[(size_t)(t0 + q) * 2 + 1] = s1 + sb[1];
    }
  }
}

extern "C" void kernel_launch(void* const* d_in, const int* in_sizes, int n_in,
                              void* d_out, int out_size, void* d_ws, size_t ws_size,
                              hipStream_t stream) {
  const int* tokens = (const int*)d_in[0];
  const unsigned char* seg = (const unsigned char*)d_in[1];
  const unsigned char* spc = (const unsigned char*)d_in[2];
  const float* emb_w = (const float*)d_in[3];
  const float* lm_w = (const float*)d_in[4];
  const float* lm_b = (const float*)d_in[5];
  const float* seg_w = (const float*)d_in[6];
  const float* seg_b = (const float*)d_in[7];

  char* ws = (char*)d_ws;
  int4* mi = (int4*)ws;                                              // 32KB @0
  unsigned* cmask = (unsigned*)(ws + (1u << 20));                    // 512KB @1MB
  int* lq = (int*)(ws + (1u << 20) + (512u << 10));                  // 8KB
  unsigned long long* lmask = (unsigned long long*)(ws + (1u << 20) + (520u << 10)); // 256B
  int2* smeta = (int2*)(ws + (1u << 20) + (524u << 10));             // 512B
  bf16_t* wbf = (bf16_t*)(ws + (2u << 20));                          // 512KB @2MB
  bf16_t* ktbLA = (bf16_t*)(ws + (3u << 20));                        // 512KB @3MB
  bf16_t* ktbLB = (bf16_t*)(ws + (3u << 20) + (512u << 10));         // 512KB
  bf16_t* vtbLA = (bf16_t*)(ws + (4u << 20));                        // 512KB @4MB
  bf16_t* vtbLB = (bf16_t*)(ws + (4u << 20) + (512u << 10));         // 512KB
  bf16_t* hbF  = (bf16_t*)(ws + (8u << 20));                         // 8MB @8MB
  bf16_t* ktbA = (bf16_t*)(ws + (16u << 20));                        // 8MB @16MB
  bf16_t* ktbB = (bf16_t*)(ws + (24u << 20));                        // 8MB @24MB
  bf16_t* vtbA = (bf16_t*)(ws + (32u << 20));                        // 8MB @32MB
  bf16_t* vtbB = (bf16_t*)(ws + (40u << 20));                        // 8MB @40MB
  float* out = (float*)d_out;
  float* outseg = out + (size_t)S * VOC;

  maskprep2<<<1, 256, 0, stream>>>(tokens, seg, spc, mi, lq, lmask, smeta);
  megaprep<<<1280, 256, 0, stream>>>(tokens, emb_w, mi, lq, lmask, lm_w, wbf, cmask,
                                     ktbA, vtbA, ktbLA, vtbLA);

  hipError_t cerr = hipErrorUnknown;
  {
    void* cargs[] = {(void*)&cmask, (void*)&mi, (void*)&smeta, (void*)&lq, (void*)&lmask,
                     (void*)&ktbA, (void*)&vtbA, (void*)&ktbLA, (void*)&vtbLA,
                     (void*)&ktbB, (void*)&vtbB, (void*)&ktbLB, (void*)&vtbLB,
                     (void*)&hbF};
    cerr = hipLaunchCooperativeKernel((const void*)coop4, dim3(NH, 64), dim3(64), cargs, 0, stream);
  }
  if (cerr != hipSuccess) {
    // fallback: one dispatch per layer (identical math and buffers)
    bf16_t* curK = ktbA;  bf16_t* curV = vtbA;
    bf16_t* nxtK = ktbB;  bf16_t* nxtV = vtbB;
    bf16_t* curKL = ktbLA; bf16_t* curVL = vtbLA;
    bf16_t* nxtKL = ktbLB; bf16_t* nxtVL = vtbLB;
    for (int L = 0; L < 4; L++) {
      attn10<<<dim3(NH, 64), 64, 0, stream>>>(curK, curV, curKL, curVL, cmask, mi, smeta, lq, lmask,
                                              nxtK, nxtV, nxtKL, nxtVL, hbF, (L < 3) ? 1 : 0);
      bf16_t* t1 = curK; curK = nxtK; nxtK = t1;
      bf16_t* t2 = curV; curV = nxtV; nxtV = t2;
      bf16_t* t3 = curKL; curKL = nxtKL; nxtKL = t3;
      bf16_t* t4 = curVL; curVL = nxtVL; nxtVL = t4;
    }
  }

  lmseg_head<<<S / 16, 256, 0, stream>>>(hbF, wbf, lm_b, seg_w, seg_b, out, outseg);
}

// Round 18
// 119.307 us; speedup vs baseline: 4.6829x; 4.6829x over previous
//
#include <hip/hip_runtime.h>

#define S 2048
#define HID 2048
#define NH 16
#define DH 128
#define VOC 128
#define LCAP 128
#define K2EXP 0.12752551286084112f   // (1/sqrt(128)) * log2(e)
#define RTHR 62.0f                   // defer-max threshold in raw-score units
#define NEGS -3.0e38f

typedef __bf16 bf16_t;
typedef __attribute__((ext_vector_type(8))) __bf16 bf16x8;
typedef __attribute__((ext_vector_type(4))) __bf16 bf16x4;
typedef __attribute__((ext_vector_type(4))) float f32x4;
typedef __attribute__((ext_vector_type(16))) float f32x16;

#define MFMA16 __builtin_amdgcn_mfma_f32_16x16x32_bf16
#define MFMA32 __builtin_amdgcn_mfma_f32_32x32x16_bf16

__device__ __forceinline__ unsigned cvtpk(float lo, float hi) {
  unsigned r;
  asm("v_cvt_pk_bf16_f32 %0, %1, %2" : "=v"(r) : "v"(lo), "v"(hi));
  return r;
}
__device__ __forceinline__ void plswap(unsigned& a, unsigned& b) {
  asm volatile("v_permlane32_swap_b32 %0, %1" : "+v"(a), "+v"(b));
}
__device__ __forceinline__ bf16x8 mk8(unsigned d0, unsigned d1, unsigned d2, unsigned d3) {
  union { unsigned u[4]; bf16x8 v; } x;
  x.u[0] = d0; x.u[1] = d1; x.u[2] = d2; x.u[3] = d3;
  return x.v;
}

// Tile layouts (per head h, 32-kv tile t; contiguous 4096 halfwords = 8KB):
//  ktb[(h*64+t)*4096 + row*128 + c*8 + e] = hid[32t+row][h*DH + 8*(c^(row&7)) + e]
//  vtb[(h*64+t)*4096 + d*32   + c*8 + e] = hid[32t + 8*(c^(d&3)) + e][h*DH + d]
// Fragment reads partition each tile across lanes (read-once) -> stage directly to VGPRs.

// ---------------- mask precompute: intervals + starts + landmarks + 32q-stripe meta ----------------
__global__ __launch_bounds__(256) void maskprep2(const int* __restrict__ tokens,
                                                 const unsigned char* __restrict__ seg,
                                                 const unsigned char* __restrict__ spc,
                                                 int4* __restrict__ mi,
                                                 int* __restrict__ lq,
                                                 unsigned long long* __restrict__ lmask,
                                                 int2* __restrict__ smeta) {
  __shared__ int ssp[257], ssg[257], smw[257], sms[257], sfl[257];
  __shared__ int fpre[2048];
  __shared__ int ns64[64];
  __shared__ unsigned long long lmk[32];
  __shared__ int cdet[2];
  int t = threadIdx.x;
  if (t < 2) cdet[t] = 0;
  if (t < 32) lmk[t] = 0ull;
  __syncthreads();
  {
    int nz = ((t & 3) != 0 && seg[t]) ? 1 : 0;
    int fc = ((t & 3) == 3 && seg[t] == 0x3f) ? 1 : 0;
    if (nz) atomicAdd(&cdet[0], 1);
    if (fc) atomicAdd(&cdet[1], 1);
  }
  __syncthreads();
  int lay = (cdet[1] > 8) ? 2 : ((cdet[0] > 4) ? 1 : 0);
  auto getb = [&](const unsigned char* p, int i) -> int {
    if (lay == 1) return p[i] != 0;
    if (lay == 2) return ((const float*)p)[i] != 0.f;
    return ((const int*)p)[i] != 0;
  };
  int base = t * 8;
  int spv[8], sgv[8], npv[8], fv[8];
  int a = 0, b = 0, mw = 0, ms = 0, fs = 0;
  for (int j = 0; j < 8; j++) {
    int i = base + j;
    spv[j] = getb(spc, i);
    sgv[j] = 1 - getb(seg, i);
    npv[j] = (tokens[i] != 127) ? 1 : 0;
    fv[j] = spv[j] & sgv[j] & npv[j];
    a += spv[j]; b += sgv[j]; fs += fv[j];
    if (i >= 1 && spv[j]) mw = (i + 1 > mw) ? i + 1 : mw;
    if (i >= 1 && sgv[j]) ms = (i + 1 > ms) ? i + 1 : ms;
  }
  ssp[t + 1] = a; ssg[t + 1] = b; smw[t + 1] = mw; sms[t + 1] = ms; sfl[t + 1] = fs;
  if (t == 0) { ssp[0] = 0; ssg[0] = 0; smw[0] = 0; sms[0] = 0; sfl[0] = 0; }
  __syncthreads();
  for (int off = 1; off < 256; off <<= 1) {
    int v0 = 0, v1 = 0, v2 = 0, v3 = 0, v4 = 0;
    if (t + 1 > off) { v0 = ssp[t+1-off]; v1 = ssg[t+1-off]; v2 = smw[t+1-off]; v3 = sms[t+1-off]; v4 = sfl[t+1-off]; }
    __syncthreads();
    ssp[t + 1] += v0; ssg[t + 1] += v1;
    if (v2 > smw[t + 1]) smw[t + 1] = v2;
    if (v3 > sms[t + 1]) sms[t + 1] = v3;
    sfl[t + 1] += v4;
    __syncthreads();
  }
  if ((t & 3) == 0) {
    int ws = smw[t], ss = sms[t];
    ns64[t >> 2] = ws < ss ? ws : ss;
  }
  int esp = ssp[t], esg = ssg[t], ef = sfl[t];
  for (int j = 0; j < 8; j++) {
    int i = base + j;
    int wint = (i == 0) ? (1 + spv[j]) : (1 + esp);
    int sint = (i == 0) ? (1 + sgv[j]) : (1 + esg);
    mi[i] = make_int4(npv[j] | (spv[j] << 1) | (sgv[j] << 2), wint, sint, 0);
    fpre[i] = ef;
    int lqv = (fv[j] && ef < LCAP) ? ef : -1;
    lq[i] = lqv;
    if (lqv >= 0) atomicOr(&lmk[i >> 6], 1ull << (i & 63));
    esp += spv[j]; esg += sgv[j]; ef += fv[j];
  }
  __syncthreads();
  if (t < 32) lmask[t] = lmk[t];
  if (t < 64) {
    int nsTile = ns64[t] >> 5;           // 32-kv tile index
    int lc = fpre[nsTile * 32];          // landmarks strictly below near zone
    if (lc > LCAP) lc = LCAP;
    smeta[t] = make_int2(nsTile, lc);
  }
}

// ---------------- megaprep: embed(ktb/vtb/landmarks) + bitgen + wcvt in one launch ----------------
__global__ __launch_bounds__(256) void megaprep(const int* __restrict__ tokens,
                                                const float* __restrict__ emb,
                                                const int4* __restrict__ mi,
                                                const int* __restrict__ lq,
                                                const unsigned long long* __restrict__ lmask,
                                                const float* __restrict__ lm_w,
                                                bf16_t* __restrict__ wbf,
                                                unsigned* __restrict__ cmask,
                                                bf16_t* __restrict__ ktb,
                                                bf16_t* __restrict__ vtb,
                                                bf16_t* __restrict__ ktbL,
                                                bf16_t* __restrict__ vtbL) {
  __shared__ __align__(16) bf16_t tile[64 * 136];
  int bid = blockIdx.x;
  int tid = threadIdx.x;

  if (bid < 512) {
    int qblk = bid & 31, h = bid >> 5;
    int q0 = qblk * 64;
    int ql = tid >> 2, d0 = (tid & 3) * 32;
    int tok = tokens[q0 + ql];
    const float4* src = (const float4*)(emb + (size_t)tok * HID + h * DH + d0);
    #pragma unroll
    for (int i = 0; i < 8; i++) {
      float4 f = src[i];
      tile[ql * 136 + d0 + i * 4 + 0] = (bf16_t)f.x;
      tile[ql * 136 + d0 + i * 4 + 1] = (bf16_t)f.y;
      tile[ql * 136 + d0 + i * 4 + 2] = (bf16_t)f.z;
      tile[ql * 136 + d0 + i * 4 + 3] = (bf16_t)f.w;
    }
    __syncthreads();
    {
      int tl2 = tid >> 7, half = (tid >> 6) & 1, lane = tid & 63;
      bf16_t* kt = ktb + ((size_t)(h * 64) + 2 * qblk + tl2) * 4096;
      #pragma unroll
      for (int k = 0; k < 4; k++) {
        int s = half * 4 + k;
        int row = s * 4 + (lane >> 4);
        int c = lane & 15;
        bf16x8 v;
        #pragma unroll
        for (int e = 0; e < 8; e++)
          v[e] = tile[(32 * tl2 + row) * 136 + 8 * (c ^ (row & 7)) + e];
        *(bf16x8*)(kt + s * 512 + lane * 8) = v;
      }
    }
    {
      int tl2 = tid >> 7, d = tid & 127;
      bf16_t* vt = vtb + ((size_t)(h * 64) + 2 * qblk + tl2) * 4096;
      #pragma unroll
      for (int c = 0; c < 4; c++) {
        bf16x8 v;
        #pragma unroll
        for (int e = 0; e < 8; e++)
          v[e] = tile[(32 * tl2 + 8 * (c ^ (d & 3)) + e) * 136 + d];
        *(bf16x8*)(vt + d * 32 + c * 8) = v;
      }
    }
    unsigned long long lm = lmask[q0 >> 6];
    while (lm) {
      int r = __builtin_ctzll(lm);
      lm &= lm - 1;
      int li = lq[q0 + r];
      if (li >= 0 && tid < 128) {
        int dd = tid;
        bf16_t vv = tile[r * 136 + dd];
        int row = li & 31, jt = li >> 5;
        ktbL[((size_t)(h * 4) + jt) * 4096 + row * 128 + ((dd >> 3) ^ (row & 7)) * 8 + (dd & 7)] = vv;
        vtbL[((size_t)(h * 4) + jt) * 4096 + dd * 32 + ((row >> 3) ^ (dd & 3)) * 8 + (row & 7)] = vv;
      }
    }
  } else if (bid < 1024) {
    __shared__ int4 km[32];
    int b2 = bid - 512;
    int w = b2 & 63, y = b2 >> 6;
    int q = y * 256 + tid;
    if (tid < 32) km[tid] = mi[w * 32 + tid];
    __syncthreads();
    int4 mq = mi[q];
    unsigned word = 0;
    #pragma unroll
    for (int j = 0; j < 32; j++) {
      int kv = w * 32 + j;
      int4 mk = km[j];
      bool v = ((mq.x & mk.x) & 1) &&
               ((mk.x & 2) || (mq.y == mk.y)) &&
               ((mk.x & 4) || (mq.z == mk.z)) &&
               (kv <= q);
      word |= (v ? 1u : 0u) << j;
    }
    cmask[(size_t)w * S + q] = word;
  } else {
    int i = (bid - 1024) * 256 + tid;
    float4 f = ((const float4*)lm_w)[i];
    bf16x4 v;
    v[0] = (bf16_t)f.x; v[1] = (bf16_t)f.y; v[2] = (bf16_t)f.z; v[3] = (bf16_t)f.w;
    *(bf16x4*)(wbf + (size_t)i * 4) = v;
  }
}

// ---------------- fused attention layer: 1 wave / 32-q stripe, register-staged K+V ----------------
__global__ __launch_bounds__(64) void attn10(const bf16_t* __restrict__ ktb,
                                             const bf16_t* __restrict__ vtb,
                                             const bf16_t* __restrict__ ktbL,
                                             const bf16_t* __restrict__ vtbL,
                                             const unsigned* __restrict__ cmask,
                                             const int4* __restrict__ mi,
                                             const int2* __restrict__ smeta,
                                             const int* __restrict__ lq,
                                             const unsigned long long* __restrict__ lmask,
                                             bf16_t* __restrict__ oktb,
                                             bf16_t* __restrict__ ovtb,
                                             bf16_t* __restrict__ oktbL,
                                             bf16_t* __restrict__ ovtbL,
                                             bf16_t* __restrict__ hbF,
                                             int writeT) {
  __shared__ __align__(16) bf16_t tl[32 * 132];   // epilogue transpose tile only

  int h = blockIdx.x, st = blockIdx.y;            // st 0..63, 32 q each
  int2 sm = smeta[st];
  int nsT = sm.x, lcount = sm.y;
  int nNear = st + 1 - nsT;
  int nLT = (lcount + 31) >> 5;
  int nIter = nNear + nLT;

  int l = threadIdx.x, l31 = l & 31, hi = l >> 5;
  int q0 = 32 * st, q = q0 + l31;
  int npq = mi[q].x & 1;
  int swz = l31 & 7;

  // Q fragments from my own ktb tile (h, st)
  bf16x8 qf[8];
  {
    const bf16_t* kt0 = ktb + ((size_t)(h * 64) + st) * 4096;
    #pragma unroll
    for (int ks = 0; ks < 8; ks++)
      qf[ks] = *(const bf16x8*)(kt0 + l31 * 128 + (((2 * ks + hi) ^ swz) * 8));
  }

  f32x16 acc[4];
  #pragma unroll
  for (int i = 0; i < 4; i++)
    #pragma unroll
    for (int r = 0; r < 16; r++) acc[i][r] = 0.f;
  float m = -1e30f, lsum = 0.f;

  auto LOADT = [&](int i, bf16x8* kf, bf16x8* vf) {
    const bf16_t* Ktile; const bf16_t* Vtile;
    if (i < nNear) {
      int t = nsT + i;
      Ktile = ktb + ((size_t)(h * 64) + t) * 4096;
      Vtile = vtb + ((size_t)(h * 64) + t) * 4096;
    } else {
      int j = i - nNear;
      Ktile = ktbL + ((size_t)(h * 4) + j) * 4096;
      Vtile = vtbL + ((size_t)(h * 4) + j) * 4096;
    }
    const bf16_t* kp = Ktile + l31 * 128;
    #pragma unroll
    for (int ks = 0; ks < 8; ks++)
      kf[ks] = *(const bf16x8*)(kp + (((2 * ks + hi) ^ swz) * 8));
    #pragma unroll
    for (int j2 = 0; j2 < 8; j2++) {
      int db = j2 >> 1, ks = j2 & 1;
      vf[j2] = *(const bf16x8*)(Vtile + (size_t)(32 * db + l31) * 32 + (((2 * ks + hi) ^ (l31 & 3)) * 8));
    }
  };

  auto COMPUTE = [&](int i, const bf16x8* kf, const bf16x8* vf) {
    unsigned w0;
    if (i < nNear) {
      w0 = cmask[(size_t)(nsT + i) * S + q];
    } else {
      int rem = lcount - (i - nNear) * 32;
      w0 = (rem >= 32) ? 0xffffffffu : ((rem <= 0) ? 0u : ((1u << rem) - 1u));
      w0 = npq ? w0 : 0u;
    }
    if (!__any(w0 != 0u)) return;

    f32x16 sA, sB;
    #pragma unroll
    for (int r = 0; r < 16; r++) { sA[r] = 0.f; sB[r] = 0.f; }
    #pragma unroll
    for (int ks = 0; ks < 8; ks += 2) {
      sA = MFMA32(kf[ks], qf[ks], sA, 0, 0, 0);
      sB = MFMA32(kf[ks + 1], qf[ks + 1], sB, 0, 0, 0);
    }

    float sv[16];
    #pragma unroll
    for (int r = 0; r < 16; r++) {
      int bit = (r & 3) + 8 * (r >> 2) + 4 * hi;
      float sr = sA[r] + sB[r];
      sv[r] = ((w0 >> bit) & 1u) ? sr : NEGS;
    }
    float t0 = fmaxf(fmaxf(sv[0], sv[1]), fmaxf(sv[2], sv[3]));
    float t1 = fmaxf(fmaxf(sv[4], sv[5]), fmaxf(sv[6], sv[7]));
    float t2 = fmaxf(fmaxf(sv[8], sv[9]), fmaxf(sv[10], sv[11]));
    float t3 = fmaxf(fmaxf(sv[12], sv[13]), fmaxf(sv[14], sv[15]));
    float mx = fmaxf(fmaxf(t0, t1), fmaxf(t2, t3));
    mx = fmaxf(mx, __shfl_xor(mx, 32, 64));
    if (__any(mx > m + RTHR)) {
      float mn = fmaxf(m, mx);
      float al = exp2f((m - mn) * K2EXP);
      m = mn; lsum *= al;
      #pragma unroll
      for (int r = 0; r < 16; r++) {
        float alr = __shfl(al, (r & 3) + 8 * (r >> 2) + 4 * hi, 64);
        #pragma unroll
        for (int d = 0; d < 4; d++) acc[d][r] *= alr;
      }
    }
    float mk = m * K2EXP;
    float p[16];
    #pragma unroll
    for (int r = 0; r < 16; r++)
      p[r] = exp2f(__builtin_fmaf(sv[r], K2EXP, -mk));
    float u0 = (p[0] + p[1]) + (p[2] + p[3]);
    float u1 = (p[4] + p[5]) + (p[6] + p[7]);
    float u2 = (p[8] + p[9]) + (p[10] + p[11]);
    float u3 = (p[12] + p[13]) + (p[14] + p[15]);
    float ps = (u0 + u1) + (u2 + u3);
    ps += __shfl_xor(ps, 32, 64);
    lsum += ps;

    bf16x8 pa[2];
    {
      unsigned a0 = cvtpk(p[0], p[1]),   a1 = cvtpk(p[2], p[3]);
      unsigned b0 = cvtpk(p[4], p[5]),   b1 = cvtpk(p[6], p[7]);
      unsigned a2 = cvtpk(p[8], p[9]),   a3 = cvtpk(p[10], p[11]);
      unsigned b2 = cvtpk(p[12], p[13]), b3 = cvtpk(p[14], p[15]);
      plswap(a0, b0); plswap(a1, b1); plswap(a2, b2); plswap(a3, b3);
      pa[0] = mk8(a0, a1, b0, b1);
      pa[1] = mk8(a2, a3, b2, b3);
    }

    #pragma unroll
    for (int db = 0; db < 4; db++) {
      #pragma unroll
      for (int ks = 0; ks < 2; ks++)
        acc[db] = MFMA32(pa[ks], vf[db * 2 + ks], acc[db], 0, 0, 0);
    }
  };

  bf16x8 kfA[8], vfA[8], kfB[8], vfB[8];
  LOADT(0, kfA, vfA);
  for (int i = 0; i < nIter; i += 2) {
    if (i + 1 < nIter) LOADT(i + 1, kfB, vfB);
    COMPUTE(i, kfA, vfA);
    if (i + 2 < nIter) LOADT(i + 2, kfA, vfA);
    if (i + 1 < nIter) COMPUTE(i + 1, kfB, vfB);
  }

  // epilogue (single wave, DS ops wave-ordered: no barriers)
  float inv = (lsum > 0.f) ? 1.f / lsum : 0.f;
  #pragma unroll
  for (int r = 0; r < 16; r++) {
    int qr = (r & 3) + 8 * (r >> 2) + 4 * hi;
    float ivr = __shfl(inv, qr, 64);
    #pragma unroll
    for (int db = 0; db < 4; db++)
      tl[qr * 132 + db * 32 + l31] = (bf16_t)(acc[db][r] * ivr);
  }
  asm volatile("s_waitcnt lgkmcnt(0)" ::: "memory");
  if (writeT) {
    bf16_t* kt = oktb + ((size_t)(h * 64) + st) * 4096;
    #pragma unroll
    for (int s = 0; s < 8; s++) {
      int row = s * 4 + (l >> 4);
      int c = l & 15;
      bf16x8 v;
      #pragma unroll
      for (int e = 0; e < 8; e++)
        v[e] = tl[row * 132 + 8 * (c ^ (row & 7)) + e];
      *(bf16x8*)(kt + s * 512 + l * 8) = v;
    }
    bf16_t* vt = ovtb + ((size_t)(h * 64) + st) * 4096;
    #pragma unroll
    for (int s = 0; s < 8; s++) {
      int d = s * 16 + (l >> 2);
      bf16x8 v;
      #pragma unroll
      for (int e = 0; e < 8; e++)
        v[e] = tl[(8 * ((l & 3) ^ (d & 3)) + e) * 132 + d];
      *(bf16x8*)(vt + s * 512 + l * 8) = v;
    }
    unsigned lm32 = (unsigned)(lmask[st >> 1] >> ((st & 1) * 32));
    while (lm32) {
      int r = __builtin_ctz(lm32);
      lm32 &= lm32 - 1;
      int li = lq[q0 + r];
      if (li >= 0) {
        int row = li & 31, jt = li >> 5;
        #pragma unroll
        for (int half = 0; half < 2; half++) {
          int dd = l + 64 * half;
          bf16_t vv = tl[r * 132 + dd];
          oktbL[((size_t)(h * 4) + jt) * 4096 + row * 128 + ((dd >> 3) ^ (row & 7)) * 8 + (dd & 7)] = vv;
          ovtbL[((size_t)(h * 4) + jt) * 4096 + dd * 32 + ((row >> 3) ^ (dd & 3)) * 8 + (row & 7)] = vv;
        }
      }
    }
  } else {
    int c4 = l & 3;
    #pragma unroll
    for (int g = 0; g < 2; g++) {
      int row = g * 16 + (l >> 2);
      #pragma unroll
      for (int k = 0; k < 4; k++) {
        bf16x8 v = *(const bf16x8*)(tl + row * 132 + c4 * 32 + k * 8);
        *(bf16x8*)(hbF + (size_t)(q0 + row) * HID + h * DH + c4 * 32 + k * 8) = v;
      }
    }
  }
}

// ---------------- lm head + segment head fused ----------------
__global__ __launch_bounds__(256) void lmseg_head(const bf16_t* __restrict__ hb,
                                                  const bf16_t* __restrict__ wbf,
                                                  const float* __restrict__ bias,
                                                  const float* __restrict__ sw,
                                                  const float* __restrict__ sb,
                                                  float* __restrict__ out,
                                                  float* __restrict__ outseg) {
  __shared__ float red[4][16][130];
  int tid = threadIdx.x;
  int w = tid >> 6, l = tid & 63, l16 = l & 15, g = l >> 4;
  int t0 = blockIdx.x * 16;
  f32x4 acc[8];
  #pragma unroll
  for (int i = 0; i < 8; i++) acc[i] = (f32x4){0.f, 0.f, 0.f, 0.f};
  const bf16_t* arow = hb + (size_t)(t0 + l16) * HID + w * 512;
  for (int k0 = 0; k0 < 512; k0 += 32) {
    bf16x8 af = *(const bf16x8*)(arow + k0 + g * 8);
    #pragma unroll
    for (int vt = 0; vt < 8; vt++) {
      bf16x8 bf_ = *(const bf16x8*)(wbf + (size_t)(vt * 16 + l16) * HID + w * 512 + k0 + g * 8);
      acc[vt] = MFMA16(af, bf_, acc[vt], 0, 0, 0);
    }
  }
  #pragma unroll
  for (int vt = 0; vt < 8; vt++)
    #pragma unroll
    for (int r = 0; r < 4; r++)
      red[w][4 * g + r][vt * 16 + l16] = acc[vt][r];
  __syncthreads();
  int q = tid >> 4, vc = (tid & 15) * 8;
  #pragma unroll
  for (int j = 0; j < 8; j++) {
    float s = red[0][q][vc + j] + red[1][q][vc + j] + red[2][q][vc + j] + red[3][q][vc + j];
    out[(size_t)(t0 + q) * VOC + vc + j] = s + bias[vc + j];
  }
  {
    int c = tid & 15;
    const bf16_t* hrow = hb + (size_t)(t0 + q) * HID + c * 128;
    float s0 = 0.f, s1 = 0.f;
    #pragma unroll
    for (int i = 0; i < 16; i++) {
      bf16x8 v = *(const bf16x8*)(hrow + i * 8);
      const float4* w0p = (const float4*)(sw + c * 128 + i * 8);
      const float4* w1p = (const float4*)(sw + HID + c * 128 + i * 8);
      float4 x0 = w0p[0], x1 = w0p[1], y0 = w1p[0], y1 = w1p[1];
      s0 += (float)v[0]*x0.x + (float)v[1]*x0.y + (float)v[2]*x0.z + (float)v[3]*x0.w
          + (float)v[4]*x1.x + (float)v[5]*x1.y + (float)v[6]*x1.z + (float)v[7]*x1.w;
      s1 += (float)v[0]*y0.x + (float)v[1]*y0.y + (float)v[2]*y0.z + (float)v[3]*y0.w
          + (float)v[4]*y1.x + (float)v[5]*y1.y + (float)v[6]*y1.z + (float)v[7]*y1.w;
    }
    #pragma unroll
    for (int off = 1; off < 16; off <<= 1) {
      s0 += __shfl_xor(s0, off, 64);
      s1 += __shfl_xor(s1, off, 64);
    }
    if (c == 0) {
      outseg[(size_t)(t0 + q) * 2] = s0 + sb[0];
      outseg[(size_t)(t0 + q) * 2 + 1] = s1 + sb[1];
    }
  }
}

extern "C" void kernel_launch(void* const* d_in, const int* in_sizes, int n_in,
                              void* d_out, int out_size, void* d_ws, size_t ws_size,
                              hipStream_t stream) {
  const int* tokens = (const int*)d_in[0];
  const unsigned char* seg = (const unsigned char*)d_in[1];
  const unsigned char* spc = (const unsigned char*)d_in[2];
  const float* emb_w = (const float*)d_in[3];
  const float* lm_w = (const float*)d_in[4];
  const float* lm_b = (const float*)d_in[5];
  const float* seg_w = (const float*)d_in[6];
  const float* seg_b = (const float*)d_in[7];

  char* ws = (char*)d_ws;
  int4* mi = (int4*)ws;                                              // 32KB @0
  unsigned* cmask = (unsigned*)(ws + (1u << 20));                    // 512KB @1MB
  int* lq = (int*)(ws + (1u << 20) + (512u << 10));                  // 8KB
  unsigned long long* lmask = (unsigned long long*)(ws + (1u << 20) + (520u << 10)); // 256B
  int2* smeta = (int2*)(ws + (1u << 20) + (524u << 10));             // 512B
  bf16_t* wbf = (bf16_t*)(ws + (2u << 20));                          // 512KB @2MB
  bf16_t* ktbLA = (bf16_t*)(ws + (3u << 20));                        // 512KB @3MB
  bf16_t* ktbLB = (bf16_t*)(ws + (3u << 20) + (512u << 10));         // 512KB
  bf16_t* vtbLA = (bf16_t*)(ws + (4u << 20));                        // 512KB @4MB
  bf16_t* vtbLB = (bf16_t*)(ws + (4u << 20) + (512u << 10));         // 512KB
  bf16_t* hbF  = (bf16_t*)(ws + (8u << 20));                         // 8MB @8MB
  bf16_t* ktbA = (bf16_t*)(ws + (16u << 20));                        // 8MB @16MB
  bf16_t* ktbB = (bf16_t*)(ws + (24u << 20));                        // 8MB @24MB
  bf16_t* vtbA = (bf16_t*)(ws + (32u << 20));                        // 8MB @32MB
  bf16_t* vtbB = (bf16_t*)(ws + (40u << 20));                        // 8MB @40MB
  float* out = (float*)d_out;
  float* outseg = out + (size_t)S * VOC;

  maskprep2<<<1, 256, 0, stream>>>(tokens, seg, spc, mi, lq, lmask, smeta);
  megaprep<<<1280, 256, 0, stream>>>(tokens, emb_w, mi, lq, lmask, lm_w, wbf, cmask,
                                     ktbA, vtbA, ktbLA, vtbLA);

  bf16_t* curK = ktbA;  bf16_t* curV = vtbA;
  bf16_t* nxtK = ktbB;  bf16_t* nxtV = vtbB;
  bf16_t* curKL = ktbLA; bf16_t* curVL = vtbLA;
  bf16_t* nxtKL = ktbLB; bf16_t* nxtVL = vtbLB;
  for (int L = 0; L < 4; L++) {
    attn10<<<dim3(NH, 64), 64, 0, stream>>>(curK, curV, curKL, curVL, cmask, mi, smeta, lq, lmask,
                                            nxtK, nxtV, nxtKL, nxtVL, hbF, (L < 3) ? 1 : 0);
    bf16_t* t1 = curK; curK = nxtK; nxtK = t1;
    bf16_t* t2 = curV; curV = nxtV; nxtV = t2;
    bf16_t* t3 = curKL; curKL = nxtKL; nxtKL = t3;
    bf16_t* t4 = curVL; curVL = nxtVL; nxtVL = t4;
  }

  lmseg_head<<<S / 16, 256, 0, stream>>>(hbF, wbf, lm_b, seg_w, seg_b, out, outseg);
}